// Round 6
// baseline (370.084 us; speedup 1.0000x reference)
//
#include <hip/hip_runtime.h>
#include <hip/hip_bf16.h>
#include <stdint.h>

typedef __bf16 bf16_t;
typedef __bf16 bf16x8 __attribute__((ext_vector_type(8)));
typedef float f32x16 __attribute__((ext_vector_type(16)));

#define TILE 128
#define BK 64   // 128x64 bf16 tile = 16 KB per matrix, 32 KB LDS total

// async 16B global -> LDS (global_load_lds_dwordx4).
// LDS dest must be wave-uniform base + lane*16 -- chunk layout guarantees it.
__device__ __forceinline__ void async_copy16(const bf16_t* g, bf16_t* l) {
    __builtin_amdgcn_global_load_lds(
        (const __attribute__((address_space(1))) unsigned int*)(uintptr_t)g,
        (__attribute__((address_space(3))) unsigned int*)(uintptr_t)l,
        16, 0, 0);
}

// supertile swizzle: sweep all mbT rows for strips of SW=8 n-cols.
// SW=8: B-strip working set 2-4MB fits per-XCD L2; halves re-fetch vs SW=4
// (R5: FETCH 82MB vs 32MB ideal -> drain latency on L2 misses).
__device__ __forceinline__ void swizzle_tiles(int bid, int mbT, int& bm, int& bn)
{
    const int SW = 8;
    int strip = bid / (mbT * SW);
    int rem   = bid - strip * (mbT * SW);
    bm = rem / SW;
    bn = strip * SW + (rem - bm * SW);
}

// NT GEMM: C[m,n] = op( sum_k A[m,k]*B[n,k] + bias )
// A: M x K row-major, B: N x K row-major (k-contiguous).
// 128x128 tile, 256 thr = 4 waves (2x2), wave 64x64 via 2x2 MFMA 32x32x16.
// LDS XOR-swizzled 8-elem chunks: chunk (row,kc) stored at row*8+(kc^(row&7)).
// AF32/BF32: operand is fp32 in global -> register-stage + cvt + ds_write_b128
// (bf16 operands use global_load_lds direct-to-LDS DMA).
// BIAS_MODE: 0=none, 1=bias[col], 2=bias[row]
template<int AF32, int BF32, bool OUT_F32, bool RELU, int BIAS_MODE>
__global__ __launch_bounds__(256, 4)
void gemm_bt(const void* __restrict__ Ap, const void* __restrict__ Bp,
             const float* __restrict__ bias, void* __restrict__ Cp,
             int K, int ldc, long sAb, long sBb, long sCb)
{
    __shared__ bf16_t As[TILE * BK];
    __shared__ bf16_t Bs[TILE * BK];

    const int b  = blockIdx.z;
    int bm, bn;
    swizzle_tiles(blockIdx.y * gridDim.x + blockIdx.x, gridDim.y, bm, bn);
    const int blockM = bm * TILE;
    const int blockN = bn * TILE;

    const int t    = threadIdx.x;
    const int lane = t & 63;
    const int wave = t >> 6;
    const int wm   = (wave >> 1) * 64;
    const int wn   = (wave & 1) * 64;
    const int r32  = lane & 31;
    const int half = lane >> 5;
    const int kx   = r32 & 7;

    f32x16 acc[2][2] = {};

    const bf16_t* Abh = (const bf16_t*)Ap + sAb * (long)b;
    const float*  Abf = (const float*) Ap + sAb * (long)b;
    const bf16_t* Bbh = (const bf16_t*)Bp + sBb * (long)b;
    const float*  Bbf = (const float*) Bp + sBb * (long)b;

    // staging: stored chunk c = t + j*256; row=c>>3, stored kc=c&7,
    // logical kc = stored ^ (row&7). 4 chunks each for A and B per K-step.
    const bf16_t* gAh[4]; const float* gAf[4];
    const bf16_t* gBh[4]; const float* gBf[4];
    bf16_t* lA[4]; bf16_t* lB[4];
    #pragma unroll
    for (int j = 0; j < 4; j++) {
        int c   = t + j * 256;
        int row = c >> 3;
        int kcl = (c & 7) ^ (row & 7);
        long ao = (long)(blockM + row) * K + kcl * 8;
        long bo = (long)(blockN + row) * K + kcl * 8;
        gAh[j] = Abh + ao;  gAf[j] = Abf + ao;
        gBh[j] = Bbh + bo;  gBf[j] = Bbf + bo;
        lA[j] = &As[c * 8];
        lB[j] = &Bs[c * 8];
    }

    for (int k0 = 0; k0 < K; k0 += BK) {
        if (AF32) {
            #pragma unroll
            for (int j = 0; j < 4; j++) {
                const float* p = gAf[j] + k0;
                float4 u0 = ((const float4*)p)[0];
                float4 u1 = ((const float4*)p)[1];
                bf16x8 w;
                w[0]=(bf16_t)u0.x; w[1]=(bf16_t)u0.y; w[2]=(bf16_t)u0.z; w[3]=(bf16_t)u0.w;
                w[4]=(bf16_t)u1.x; w[5]=(bf16_t)u1.y; w[6]=(bf16_t)u1.z; w[7]=(bf16_t)u1.w;
                *(bf16x8*)lA[j] = w;
            }
        } else {
            #pragma unroll
            for (int j = 0; j < 4; j++) async_copy16(gAh[j] + k0, lA[j]);
        }
        if (BF32) {
            #pragma unroll
            for (int j = 0; j < 4; j++) {
                const float* p = gBf[j] + k0;
                float4 u0 = ((const float4*)p)[0];
                float4 u1 = ((const float4*)p)[1];
                bf16x8 w;
                w[0]=(bf16_t)u0.x; w[1]=(bf16_t)u0.y; w[2]=(bf16_t)u0.z; w[3]=(bf16_t)u0.w;
                w[4]=(bf16_t)u1.x; w[5]=(bf16_t)u1.y; w[6]=(bf16_t)u1.z; w[7]=(bf16_t)u1.w;
                *(bf16x8*)lB[j] = w;
            }
        } else {
            #pragma unroll
            for (int j = 0; j < 4; j++) async_copy16(gBh[j] + k0, lB[j]);
        }
        __syncthreads();

        #pragma unroll
        for (int ks = 0; ks < 4; ks++) {
            const int kc = ks * 2 + half;
            bf16x8 af[2], bfr[2];
            #pragma unroll
            for (int i = 0; i < 2; i++) {
                int R = wm + i * 32 + r32;
                af[i] = *(const bf16x8*)&As[(R * 8 + (kc ^ kx)) * 8];
            }
            #pragma unroll
            for (int j = 0; j < 2; j++) {
                int C = wn + j * 32 + r32;
                bfr[j] = *(const bf16x8*)&Bs[(C * 8 + (kc ^ kx)) * 8];
            }
            #pragma unroll
            for (int i = 0; i < 2; i++)
                #pragma unroll
                for (int j = 0; j < 2; j++)
                    acc[i][j] = __builtin_amdgcn_mfma_f32_32x32x16_bf16(
                                    af[i], bfr[j], acc[i][j], 0, 0, 0);
        }
        __syncthreads();
    }

    // epilogue: C/D layout col=lane&31, row=(reg&3)+8*(reg>>2)+4*half
    float*  Cf = (float*) Cp + sCb * (long)b;
    bf16_t* Ch = (bf16_t*)Cp + sCb * (long)b;
    #pragma unroll
    for (int ti = 0; ti < 2; ti++) {
        #pragma unroll
        for (int tj = 0; tj < 2; tj++) {
            const int gcol = blockN + wn + tj * 32 + r32;
            float bc = 0.f;
            if (BIAS_MODE == 1) bc = bias[gcol];
            #pragma unroll
            for (int reg = 0; reg < 16; reg++) {
                const int grow = blockM + wm + ti * 32
                               + (reg & 3) + 8 * (reg >> 2) + 4 * half;
                float vv = acc[ti][tj][reg];
                if (BIAS_MODE == 1) vv += bc;
                if (BIAS_MODE == 2) vv += bias[grow];
                if (RELU) vv = fmaxf(vv, 0.f);
                if (OUT_F32) Cf[(long)grow * ldc + gcol] = vv;
                else         Ch[(long)grow * ldc + gcol] = (bf16_t)vv;
            }
        }
    }
}

// Small cast: Wq, Wk, Wv (3 x 1M fp32) -> bf16. 393216 threads x 8 elems.
__global__ __launch_bounds__(256)
void cast_w_kernel(const float* __restrict__ Wq, const float* __restrict__ Wk,
                   const float* __restrict__ Wv, bf16_t* __restrict__ ws)
{
    long id = (long)blockIdx.x * blockDim.x + threadIdx.x;   // < 393216
    int s = (int)(id >> 17);                 // /131072 -> 0,1,2
    long off = (id & 131071) * 8;
    const float* src = (s == 0 ? Wq : s == 1 ? Wk : Wv) + off;
    bf16_t* dst = ws + (long)s * 1048576 + off;
    float4 v0 = ((const float4*)src)[0];
    float4 v1 = ((const float4*)src)[1];
    alignas(16) bf16_t o[8];
    o[0]=(bf16_t)v0.x; o[1]=(bf16_t)v0.y; o[2]=(bf16_t)v0.z; o[3]=(bf16_t)v0.w;
    o[4]=(bf16_t)v1.x; o[5]=(bf16_t)v1.y; o[6]=(bf16_t)v1.z; o[7]=(bf16_t)v1.w;
    *(uint4*)dst = *(const uint4*)o;
}

extern "C" void kernel_launch(void* const* d_in, const int* in_sizes, int n_in,
                              void* d_out, int out_size, void* d_ws, size_t ws_size,
                              hipStream_t stream)
{
    const float* q   = (const float*)d_in[0];
    const float* k   = (const float*)d_in[1];
    const float* v   = (const float*)d_in[2];
    const float* Wq  = (const float*)d_in[3];
    const float* bq  = (const float*)d_in[4];
    const float* Wk  = (const float*)d_in[5];
    const float* bk  = (const float*)d_in[6];
    const float* Wv  = (const float*)d_in[7];
    const float* bv  = (const float*)d_in[8];

    const int B = 4, S = 2048, D = 1024;
    const int BS = B * S; // 8192

    // workspace (bf16 element offsets):
    //   Wqb 0, Wkb 1048576, Wvb 2097152
    //   Qp 3145728 (8388608), Kp 11534336, VpT 19922944
    //   Sc 28311552 (16777216)           total ~90 MB
    bf16_t* ws  = (bf16_t*)d_ws;
    bf16_t* Wqb = ws;
    bf16_t* Wkb = ws + 1048576L;
    bf16_t* Wvb = ws + 2097152L;
    bf16_t* Qp  = ws + 3145728L;
    bf16_t* Kp  = ws + 11534336L;
    bf16_t* VpT = ws + 19922944L;
    bf16_t* Sc  = ws + 28311552L;

    dim3 blk(256);

    // 1) cast W matrices only (q,k,v convert in-flight during proj staging)
    cast_w_kernel<<<dim3(1536), blk, 0, stream>>>(Wq, Wk, Wv, ws);

    // 2) Qp = q @ Wqb^T + bq   [M=8192, N=1024, K=1024]; A fp32 reg-staged
    gemm_bt<1, 0, false, false, 1><<<dim3(D / TILE, BS / TILE, 1), blk, 0, stream>>>(
        q, Wqb, bq, Qp, D, D, 0L, 0L, 0L);

    // 3) Kp = k @ Wkb^T + bk
    gemm_bt<1, 0, false, false, 1><<<dim3(D / TILE, BS / TILE, 1), blk, 0, stream>>>(
        k, Wkb, bk, Kp, D, D, 0L, 0L, 0L);

    // 4) VpT[b] = (v_b @ Wv^T + bv)^T : A=Wvb bf16 async, B=v_b fp32 reg-staged
    gemm_bt<0, 1, false, false, 2><<<dim3(S / TILE, D / TILE, B), blk, 0, stream>>>(
        Wvb, v, bv, VpT, D, S, 0L, (long)S * D, (long)D * S);

    // 5) Sc[b] = relu(Qp_b @ Kp_b^T)  [2048 x 2048, K=1024], bf16 out
    gemm_bt<0, 0, false, true, 0><<<dim3(S / TILE, S / TILE, B), blk, 0, stream>>>(
        Qp, Kp, nullptr, Sc, D, S, (long)S * D, (long)S * D, (long)S * S);

    // 6) out[b] = Sc_b @ VpT_b^T  [2048 x 1024, K=2048], fp32 out
    gemm_bt<0, 0, true, false, 0><<<dim3(D / TILE, S / TILE, B), blk, 0, stream>>>(
        Sc, VpT, nullptr, d_out, S, D, (long)S * S, (long)D * S, (long)S * D);
}

// Round 7
// 336.520 us; speedup vs baseline: 1.0997x; 1.0997x over previous
//
#include <hip/hip_runtime.h>
#include <hip/hip_bf16.h>
#include <stdint.h>

typedef __bf16 bf16_t;
typedef __bf16 bf16x8 __attribute__((ext_vector_type(8)));
typedef float f32x16 __attribute__((ext_vector_type(16)));

#define TM 256     // block tile M
#define TN 128     // block tile N
#define BK 64      // K per stage; LDS = 256*64*2 + 128*64*2 = 48 KB

// async 16B global -> LDS (global_load_lds_dwordx4).
// LDS dest must be wave-uniform base + lane*16 -- chunk layout guarantees it.
__device__ __forceinline__ void async_copy16(const bf16_t* g, bf16_t* l) {
    __builtin_amdgcn_global_load_lds(
        (const __attribute__((address_space(1))) unsigned int*)(uintptr_t)g,
        (__attribute__((address_space(3))) unsigned int*)(uintptr_t)l,
        16, 0, 0);
}

// NT GEMM, all-bf16: C[m,n] = op( sum_k A[m,k]*B[n,k] + bias )
// Block 256x128, 256 thr = 4 waves (2x2), wave tile 128x64 = 4x2 MFMA 32x32x16.
// Rationale (R6 post-mortem): 64x64 wave tile is LDS-pipe-bound (256 LDS-cyc vs
// 128 matrix-cyc per iter); 128x64 gives 6 reads per 8 MFMAs -> matrix-bound.
// LDS XOR-swizzle: chunk (row,kc) stored at row*8 + (kc ^ (row&7)).
// BIAS_MODE: 0=none, 1=bias[col], 2=bias[row]
template<bool OUT_F32, bool RELU, int BIAS_MODE>
__global__ __launch_bounds__(256, 2)
void gemm_bt(const bf16_t* __restrict__ A, const bf16_t* __restrict__ B,
             const float* __restrict__ bias, void* __restrict__ Cp,
             int K, int ldc, long sAb, long sBb, long sCb)
{
    __shared__ bf16_t As[TM * BK];   // 32 KB
    __shared__ bf16_t Bs[TN * BK];   // 16 KB

    const int b = blockIdx.z;
    // supertile swizzle: sweep all M-tiles for strips of SW=4 n-cols (L2 reuse)
    const int SW = 4;
    const int mbT = gridDim.y;
    int bid   = blockIdx.y * gridDim.x + blockIdx.x;
    int strip = bid / (mbT * SW);
    int rem   = bid - strip * (mbT * SW);
    int bm    = rem / SW;
    int bn    = strip * SW + (rem - bm * SW);
    const int blockM = bm * TM;
    const int blockN = bn * TN;

    const int t    = threadIdx.x;
    const int lane = t & 63;
    const int wave = t >> 6;
    const int wm   = (wave >> 1) * 128;   // wave m-origin (0 or 128)
    const int wn   = (wave & 1) * 64;     // wave n-origin (0 or 64)
    const int r32  = lane & 31;
    const int half = lane >> 5;           // k-half selector
    const int kx   = r32 & 7;             // xor key (row&7 == r32&7 for all frags)

    f32x16 acc[4][2] = {};

    const bf16_t* Ab = A + sAb * (long)b;
    const bf16_t* Bb = B + sBb * (long)b;

    // staging: A = 2048 chunks (8/thread), B = 1024 chunks (4/thread).
    // chunk c: row=c>>3, stored kc=c&7, logical kc = stored ^ (row&7).
    const bf16_t* gA[8]; bf16_t* lA[8];
    const bf16_t* gB[4]; bf16_t* lB[4];
    #pragma unroll
    for (int j = 0; j < 8; j++) {
        int c   = t + j * 256;
        int row = c >> 3;
        int kcl = (c & 7) ^ (row & 7);
        gA[j] = Ab + (long)(blockM + row) * K + kcl * 8;
        lA[j] = &As[c * 8];
    }
    #pragma unroll
    for (int j = 0; j < 4; j++) {
        int c   = t + j * 256;
        int row = c >> 3;
        int kcl = (c & 7) ^ (row & 7);
        gB[j] = Bb + (long)(blockN + row) * K + kcl * 8;
        lB[j] = &Bs[c * 8];
    }

    for (int k0 = 0; k0 < K; k0 += BK) {
        #pragma unroll
        for (int j = 0; j < 8; j++) async_copy16(gA[j] + k0, lA[j]);
        #pragma unroll
        for (int j = 0; j < 4; j++) async_copy16(gB[j] + k0, lB[j]);
        __syncthreads();

        #pragma unroll
        for (int ks = 0; ks < 4; ks++) {
            const int kc = ks * 2 + half;
            bf16x8 af[4], bf[2];
            #pragma unroll
            for (int i = 0; i < 4; i++) {
                int R = wm + i * 32 + r32;
                af[i] = *(const bf16x8*)&As[(R * 8 + (kc ^ kx)) * 8];
            }
            #pragma unroll
            for (int j = 0; j < 2; j++) {
                int C = wn + j * 32 + r32;
                bf[j] = *(const bf16x8*)&Bs[(C * 8 + (kc ^ kx)) * 8];
            }
            #pragma unroll
            for (int i = 0; i < 4; i++)
                #pragma unroll
                for (int j = 0; j < 2; j++)
                    acc[i][j] = __builtin_amdgcn_mfma_f32_32x32x16_bf16(
                                    af[i], bf[j], acc[i][j], 0, 0, 0);
        }
        __syncthreads();
    }

    // epilogue: C/D layout col=lane&31, row=(reg&3)+8*(reg>>2)+4*half
    float*  Cf = (float*) Cp + sCb * (long)b;
    bf16_t* Ch = (bf16_t*)Cp + sCb * (long)b;
    #pragma unroll
    for (int ti = 0; ti < 4; ti++) {
        #pragma unroll
        for (int tj = 0; tj < 2; tj++) {
            const int gcol = blockN + wn + tj * 32 + r32;
            float bc = 0.f;
            if (BIAS_MODE == 1) bc = bias[gcol];
            #pragma unroll
            for (int reg = 0; reg < 16; reg++) {
                const int grow = blockM + wm + ti * 32
                               + (reg & 3) + 8 * (reg >> 2) + 4 * half;
                float vv = acc[ti][tj][reg];
                if (BIAS_MODE == 1) vv += bc;
                if (BIAS_MODE == 2) vv += bias[grow];
                if (RELU) vv = fmaxf(vv, 0.f);
                if (OUT_F32) Cf[(long)grow * ldc + gcol] = vv;
                else         Ch[(long)grow * ldc + gcol] = (bf16_t)vv;
            }
        }
    }
}

// One-shot fp32 -> bf16 cast of q,k,v,Wq,Wk,Wv into workspace.
__global__ __launch_bounds__(256)
void cast_all_kernel(const float* __restrict__ q, const float* __restrict__ k,
                     const float* __restrict__ v, const float* __restrict__ Wq,
                     const float* __restrict__ Wk, const float* __restrict__ Wv,
                     bf16_t* __restrict__ ws)
{
    const long BIG = 1048576;   // 8192*1024 / 8
    const long SMALL = 131072;  // 1024*1024 / 8
    long id = (long)blockIdx.x * blockDim.x + threadIdx.x;
    const float* src; bf16_t* dst;
    if (id < 3 * BIG) {
        int s = (int)(id / BIG);
        long off = (id - (long)s * BIG) * 8;
        src = (s == 0 ? q : s == 1 ? k : v) + off;
        dst = ws + (long)s * 8388608 + off;
    } else {
        long id2 = id - 3 * BIG;
        int s = (int)(id2 / SMALL);
        long off = (id2 - (long)s * SMALL) * 8;
        src = (s == 0 ? Wq : s == 1 ? Wk : Wv) + off;
        dst = ws + 25165824L + (long)s * 1048576 + off;
    }
    float4 v0 = ((const float4*)src)[0];
    float4 v1 = ((const float4*)src)[1];
    alignas(16) bf16_t o[8];
    o[0]=(bf16_t)v0.x; o[1]=(bf16_t)v0.y; o[2]=(bf16_t)v0.z; o[3]=(bf16_t)v0.w;
    o[4]=(bf16_t)v1.x; o[5]=(bf16_t)v1.y; o[6]=(bf16_t)v1.z; o[7]=(bf16_t)v1.w;
    *(uint4*)dst = *(const uint4*)o;
}

extern "C" void kernel_launch(void* const* d_in, const int* in_sizes, int n_in,
                              void* d_out, int out_size, void* d_ws, size_t ws_size,
                              hipStream_t stream)
{
    const float* q   = (const float*)d_in[0];
    const float* k   = (const float*)d_in[1];
    const float* v   = (const float*)d_in[2];
    const float* Wq  = (const float*)d_in[3];
    const float* bq  = (const float*)d_in[4];
    const float* Wk  = (const float*)d_in[5];
    const float* bk  = (const float*)d_in[6];
    const float* Wv  = (const float*)d_in[7];
    const float* bv  = (const float*)d_in[8];

    const int B = 4, S = 2048, D = 1024;
    const int BS = B * S; // 8192

    // workspace (bf16 element offsets):
    //   qb 0, kb 8388608, vb 16777216 (dead after their GEMM; Sc aliases qb+kb)
    //   Wqb 25165824, Wkb 26214400, Wvb 27262976
    //   Qp 28311552, Kp 36700160, VpT 45088768   (total ~107 MB)
    bf16_t* ws  = (bf16_t*)d_ws;
    bf16_t* qb  = ws;
    bf16_t* kb  = ws + 8388608L;
    bf16_t* vb  = ws + 16777216L;
    bf16_t* Wqb = ws + 25165824L;
    bf16_t* Wkb = ws + 26214400L;
    bf16_t* Wvb = ws + 27262976L;
    bf16_t* Qp  = ws + 28311552L;
    bf16_t* Kp  = ws + 36700160L;
    bf16_t* VpT = ws + 45088768L;
    bf16_t* Sc  = ws;              // aliases qb+kb (both dead by step 5)

    dim3 blk(256);

    // 1) cast everything to bf16 (R6 lesson: in-flight fp32 staging kills async DMA)
    cast_all_kernel<<<dim3(13824), blk, 0, stream>>>(q, k, v, Wq, Wk, Wv, ws);

    // 2) Qp = qb @ Wqb^T + bq   [M=8192, N=1024, K=1024]  grid 8x32
    gemm_bt<false, false, 1><<<dim3(D / TN, BS / TM, 1), blk, 0, stream>>>(
        qb, Wqb, bq, Qp, D, D, 0L, 0L, 0L);

    // 3) Kp = kb @ Wkb^T + bk
    gemm_bt<false, false, 1><<<dim3(D / TN, BS / TM, 1), blk, 0, stream>>>(
        kb, Wkb, bk, Kp, D, D, 0L, 0L, 0L);

    // 4) VpT[b] = (v_b @ Wv^T + bv)^T : A=Wvb [1024,1024], B=vb_b [2048,1024]
    //    grid 16x4x4, row bias
    gemm_bt<false, false, 2><<<dim3(S / TN, D / TM, B), blk, 0, stream>>>(
        Wvb, vb, bv, VpT, D, S, 0L, (long)S * D, (long)D * S);

    // 5) Sc[b] = relu(Qp_b @ Kp_b^T)  [2048 x 2048, K=1024]  grid 16x8x4
    gemm_bt<false, true, 0><<<dim3(S / TN, S / TM, B), blk, 0, stream>>>(
        Qp, Kp, nullptr, Sc, D, S, (long)S * D, (long)S * D, (long)S * S);

    // 6) out[b] = Sc_b @ VpT_b^T  [2048 x 1024, K=2048]  grid 8x8x4, fp32 out
    gemm_bt<true, false, 0><<<dim3(D / TN, S / TM, B), blk, 0, stream>>>(
        Sc, VpT, nullptr, d_out, S, D, (long)S * S, (long)D * S, (long)S * D);
}

// Round 8
// 318.865 us; speedup vs baseline: 1.1606x; 1.0554x over previous
//
#include <hip/hip_runtime.h>
#include <hip/hip_bf16.h>
#include <stdint.h>

typedef __bf16 bf16_t;
typedef __bf16 bf16x8 __attribute__((ext_vector_type(8)));
typedef float f32x16 __attribute__((ext_vector_type(16)));

#define TILE 128
#define BK 64

// async 16B global -> LDS (global_load_lds_dwordx4).
// LDS dest must be wave-uniform base + lane*16 -- chunk layout guarantees it.
__device__ __forceinline__ void async_copy16(const void* g, void* l) {
    __builtin_amdgcn_global_load_lds(
        (const __attribute__((address_space(1))) unsigned int*)(uintptr_t)g,
        (__attribute__((address_space(3))) unsigned int*)(uintptr_t)l,
        16, 0, 0);
}

__device__ __forceinline__ bf16x8 cvt8(float4 lo, float4 hi) {
    bf16x8 w;
    w[0]=(bf16_t)lo.x; w[1]=(bf16_t)lo.y; w[2]=(bf16_t)lo.z; w[3]=(bf16_t)lo.w;
    w[4]=(bf16_t)hi.x; w[5]=(bf16_t)hi.y; w[6]=(bf16_t)hi.z; w[7]=(bf16_t)hi.w;
    return w;
}

// NT GEMM: C[m,n] = op( sum_k A[m,k]*B[n,k] + bias )
// R5-proven core: 128x128 tile, 4 waves (2x2), wave 64x64 = 2x2 MFMA 32x32x16,
// BK=64, XOR-swizzled LDS, SW=4 supertile. AF32/BF32: that operand is fp32 in
// global; it is DMA'd to LDS *as fp32* (16B = 4-float chunks, swizzled) and
// converted to bf16 at fragment-read time (keeps async DMA -- R6 lesson).
// BIAS_MODE: 0=none, 1=bias[col], 2=bias[row]
template<int AF32, int BF32, bool OUT_F32, bool RELU, int BIAS_MODE>
__global__ __launch_bounds__(256, 4)
void gemm_bt(const void* __restrict__ Ap, const void* __restrict__ Bp,
             const float* __restrict__ bias, void* __restrict__ Cp,
             int K, int ldc, long sAb, long sBb, long sCb)
{
    __shared__ __align__(16) char AsRaw[TILE * BK * (AF32 ? 4 : 2)];
    __shared__ __align__(16) char BsRaw[TILE * BK * (BF32 ? 4 : 2)];

    const int b = blockIdx.z;
    // supertile swizzle SW=4 (R5-proven)
    const int SW = 4;
    const int mbT = gridDim.y;
    int bid   = blockIdx.y * gridDim.x + blockIdx.x;
    int strip = bid / (mbT * SW);
    int rem   = bid - strip * (mbT * SW);
    int bm    = rem / SW;
    int bn    = strip * SW + (rem - bm * SW);
    const int blockM = bm * TILE;
    const int blockN = bn * TILE;

    const int t    = threadIdx.x;
    const int lane = t & 63;
    const int wave = t >> 6;
    const int wm   = (wave >> 1) * 64;
    const int wn   = (wave & 1) * 64;
    const int r32  = lane & 31;
    const int half = lane >> 5;
    const int kx   = r32 & 7;          // xor key (== row&7 for all frag rows)

    f32x16 acc[2][2] = {};

    // ---- staging address setup ----
    // bf16 operand: 1024 chunks of 8 bf16; chunk c: row=c>>3, kcl=(c&7)^(row&7)
    // fp32 operand: 2048 chunks of 4 f32;  chunk c: row=c>>4, fc=(c&15)^(row&7)
    constexpr int NA = AF32 ? 8 : 4;
    constexpr int NB = BF32 ? 8 : 4;
    const char* gA[8]; void* lA[8];
    const char* gB[8]; void* lB[8];
    {
        const char* Ab = (const char*)Ap + sAb * (long)b * (AF32 ? 4 : 2);
        const char* Bb = (const char*)Bp + sBb * (long)b * (BF32 ? 4 : 2);
        #pragma unroll
        for (int j = 0; j < NA; j++) {
            int c = t + j * 256;
            if (AF32) {
                int row = c >> 4, fc = (c & 15) ^ (row & 7);
                gA[j] = Ab + ((long)(blockM + row) * K + fc * 4) * 4;
            } else {
                int row = c >> 3, kcl = (c & 7) ^ (row & 7);
                gA[j] = Ab + ((long)(blockM + row) * K + kcl * 8) * 2;
            }
            lA[j] = AsRaw + c * 16;
        }
        #pragma unroll
        for (int j = 0; j < NB; j++) {
            int c = t + j * 256;
            if (BF32) {
                int row = c >> 4, fc = (c & 15) ^ (row & 7);
                gB[j] = Bb + ((long)(blockN + row) * K + fc * 4) * 4;
            } else {
                int row = c >> 3, kcl = (c & 7) ^ (row & 7);
                gB[j] = Bb + ((long)(blockN + row) * K + kcl * 8) * 2;
            }
            lB[j] = BsRaw + c * 16;
        }
    }

    for (int k0 = 0; k0 < K; k0 += BK) {
        const long aoff = (long)k0 * (AF32 ? 4 : 2);
        const long boff = (long)k0 * (BF32 ? 4 : 2);
        #pragma unroll
        for (int j = 0; j < NA; j++) async_copy16(gA[j] + aoff, lA[j]);
        #pragma unroll
        for (int j = 0; j < NB; j++) async_copy16(gB[j] + boff, lB[j]);
        __syncthreads();

        #pragma unroll
        for (int ks = 0; ks < 4; ks++) {
            const int kc = ks * 2 + half;        // 8-elem k-chunk index in BK
            bf16x8 af[2], bfr[2];
            #pragma unroll
            for (int i = 0; i < 2; i++) {
                int R = wm + i * 32 + r32;
                if (AF32) {
                    const float* Asf = (const float*)AsRaw;
                    int f0 = (2 * kc) ^ kx, f1 = (2 * kc + 1) ^ kx;
                    float4 lo = *(const float4*)&Asf[(R * 16 + f0) * 4];
                    float4 hi = *(const float4*)&Asf[(R * 16 + f1) * 4];
                    af[i] = cvt8(lo, hi);
                } else {
                    const bf16_t* Ash = (const bf16_t*)AsRaw;
                    af[i] = *(const bf16x8*)&Ash[(R * 8 + (kc ^ kx)) * 8];
                }
            }
            #pragma unroll
            for (int j = 0; j < 2; j++) {
                int C = wn + j * 32 + r32;
                if (BF32) {
                    const float* Bsf = (const float*)BsRaw;
                    int f0 = (2 * kc) ^ kx, f1 = (2 * kc + 1) ^ kx;
                    float4 lo = *(const float4*)&Bsf[(C * 16 + f0) * 4];
                    float4 hi = *(const float4*)&Bsf[(C * 16 + f1) * 4];
                    bfr[j] = cvt8(lo, hi);
                } else {
                    const bf16_t* Bsh = (const bf16_t*)BsRaw;
                    bfr[j] = *(const bf16x8*)&Bsh[(C * 8 + (kc ^ kx)) * 8];
                }
            }
            #pragma unroll
            for (int i = 0; i < 2; i++)
                #pragma unroll
                for (int j = 0; j < 2; j++)
                    acc[i][j] = __builtin_amdgcn_mfma_f32_32x32x16_bf16(
                                    af[i], bfr[j], acc[i][j], 0, 0, 0);
        }
        __syncthreads();
    }

    // epilogue: C/D layout col=lane&31, row=(reg&3)+8*(reg>>2)+4*half
    float*  Cf = (float*) Cp + sCb * (long)b;
    bf16_t* Ch = (bf16_t*)Cp + sCb * (long)b;
    #pragma unroll
    for (int ti = 0; ti < 2; ti++) {
        #pragma unroll
        for (int tj = 0; tj < 2; tj++) {
            const int gcol = blockN + wn + tj * 32 + r32;
            float bc = 0.f;
            if (BIAS_MODE == 1) bc = bias[gcol];
            #pragma unroll
            for (int reg = 0; reg < 16; reg++) {
                const int grow = blockM + wm + ti * 32
                               + (reg & 3) + 8 * (reg >> 2) + 4 * half;
                float vv = acc[ti][tj][reg];
                if (BIAS_MODE == 1) vv += bc;
                if (BIAS_MODE == 2) vv += bias[grow];
                if (RELU) vv = fmaxf(vv, 0.f);
                if (OUT_F32) Cf[(long)grow * ldc + gcol] = vv;
                else         Ch[(long)grow * ldc + gcol] = (bf16_t)vv;
            }
        }
    }
}

// Small cast: Wq, Wk, Wv (3 x 1M fp32) -> bf16. 393216 threads x 8 elems.
__global__ __launch_bounds__(256)
void cast_w_kernel(const float* __restrict__ Wq, const float* __restrict__ Wk,
                   const float* __restrict__ Wv, bf16_t* __restrict__ ws)
{
    long id = (long)blockIdx.x * blockDim.x + threadIdx.x;   // < 393216
    int s = (int)(id >> 17);                 // 0,1,2
    long off = (id & 131071) * 8;
    const float* src = (s == 0 ? Wq : s == 1 ? Wk : Wv) + off;
    bf16_t* dst = ws + (long)s * 1048576 + off;
    float4 v0 = ((const float4*)src)[0];
    float4 v1 = ((const float4*)src)[1];
    alignas(16) bf16_t o[8];
    o[0]=(bf16_t)v0.x; o[1]=(bf16_t)v0.y; o[2]=(bf16_t)v0.z; o[3]=(bf16_t)v0.w;
    o[4]=(bf16_t)v1.x; o[5]=(bf16_t)v1.y; o[6]=(bf16_t)v1.z; o[7]=(bf16_t)v1.w;
    *(uint4*)dst = *(const uint4*)o;
}

extern "C" void kernel_launch(void* const* d_in, const int* in_sizes, int n_in,
                              void* d_out, int out_size, void* d_ws, size_t ws_size,
                              hipStream_t stream)
{
    const float* q   = (const float*)d_in[0];
    const float* k   = (const float*)d_in[1];
    const float* v   = (const float*)d_in[2];
    const float* Wq  = (const float*)d_in[3];
    const float* bq  = (const float*)d_in[4];
    const float* Wk  = (const float*)d_in[5];
    const float* bk  = (const float*)d_in[6];
    const float* Wv  = (const float*)d_in[7];
    const float* bv  = (const float*)d_in[8];

    const int B = 4, S = 2048, D = 1024;
    const int BS = B * S; // 8192

    // workspace (bf16 element offsets): no q/k/v copies needed anymore.
    //   Wqb 0, Wkb 1048576, Wvb 2097152
    //   Qp 3145728 (8388608), Kp 11534336, VpT 19922944, Sc 28311552 (16777216)
    //   total ~90 MB
    bf16_t* ws  = (bf16_t*)d_ws;
    bf16_t* Wqb = ws;
    bf16_t* Wkb = ws + 1048576L;
    bf16_t* Wvb = ws + 2097152L;
    bf16_t* Qp  = ws + 3145728L;
    bf16_t* Kp  = ws + 11534336L;
    bf16_t* VpT = ws + 19922944L;
    bf16_t* Sc  = ws + 28311552L;

    dim3 blk(256);

    // 1) cast W matrices only (q,k,v DMA'd fp32 -> LDS, cvt at frag read)
    cast_w_kernel<<<dim3(1536), blk, 0, stream>>>(Wq, Wk, Wv, ws);

    // 2) Qp = q @ Wqb^T + bq   [M=8192, N=1024, K=1024]; A fp32-in-LDS
    gemm_bt<1, 0, false, false, 1><<<dim3(D / TILE, BS / TILE, 1), blk, 0, stream>>>(
        q, Wqb, bq, Qp, D, D, 0L, 0L, 0L);

    // 3) Kp = k @ Wkb^T + bk
    gemm_bt<1, 0, false, false, 1><<<dim3(D / TILE, BS / TILE, 1), blk, 0, stream>>>(
        k, Wkb, bk, Kp, D, D, 0L, 0L, 0L);

    // 4) VpT[b] = (v_b @ Wv^T + bv)^T : A=Wvb bf16, B=v_b fp32-in-LDS, row bias
    gemm_bt<0, 1, false, false, 2><<<dim3(S / TILE, D / TILE, B), blk, 0, stream>>>(
        Wvb, v, bv, VpT, D, S, 0L, (long)S * D, (long)D * S);

    // 5) Sc[b] = relu(Qp_b @ Kp_b^T)  [2048 x 2048, K=1024], bf16 out (R5-exact)
    gemm_bt<0, 0, false, true, 0><<<dim3(S / TILE, S / TILE, B), blk, 0, stream>>>(
        Qp, Kp, nullptr, Sc, D, S, (long)S * D, (long)S * D, (long)S * S);

    // 6) out[b] = Sc_b @ VpT_b^T  [2048 x 1024, K=2048], fp32 out (R5-exact)
    gemm_bt<0, 0, true, false, 0><<<dim3(D / TILE, S / TILE, B), blk, 0, stream>>>(
        Sc, VpT, nullptr, d_out, S, D, (long)S * S, (long)D * S, (long)S * D);
}

// Round 9
// 318.535 us; speedup vs baseline: 1.1618x; 1.0010x over previous
//
#include <hip/hip_runtime.h>
#include <hip/hip_bf16.h>
#include <stdint.h>

typedef __bf16 bf16_t;
typedef __bf16 bf16x8 __attribute__((ext_vector_type(8)));
typedef float f32x16 __attribute__((ext_vector_type(16)));

#define TILE 128
#define BK 64   // 128x64 bf16 tile = 16 KB per matrix, 32 KB LDS total

// async 16B global -> LDS (global_load_lds_dwordx4).
// LDS dest must be wave-uniform base + lane*16 -- chunk layout guarantees it.
__device__ __forceinline__ void async_copy16(const bf16_t* g, bf16_t* l) {
    __builtin_amdgcn_global_load_lds(
        (const __attribute__((address_space(1))) unsigned int*)(uintptr_t)g,
        (__attribute__((address_space(3))) unsigned int*)(uintptr_t)l,
        16, 0, 0);
}

// NT GEMM, all-bf16: C[m,n] = op( sum_k A[m,k]*B[n,k] + bias )
// R5-proven core: 128x128 tile, 4 waves (2x2), wave 64x64 via 2x2 MFMA 32x32x16,
// BK=64, XOR-swizzled LDS chunks, global_load_lds staging.
// SW = supertile width (n-tiles per L2-resident strip): 4 for projections
// (W fits L2 anyway), 8 for Sc/out (halves A re-fetch: 82->~50 MB predicted).
// BIAS_MODE: 0=none, 1=bias[col], 2=bias[row]
template<int SW, bool OUT_F32, bool RELU, int BIAS_MODE>
__global__ __launch_bounds__(256, 4)
void gemm_bt(const bf16_t* __restrict__ A, const bf16_t* __restrict__ B,
             const float* __restrict__ bias, void* __restrict__ Cp,
             int K, int ldc, long sAb, long sBb, long sCb)
{
    __shared__ bf16_t As[TILE * BK];
    __shared__ bf16_t Bs[TILE * BK];

    const int b = blockIdx.z;
    const int mbT = gridDim.y;
    int bid   = blockIdx.y * gridDim.x + blockIdx.x;
    int strip = bid / (mbT * SW);
    int rem   = bid - strip * (mbT * SW);
    int bm    = rem / SW;
    int bn    = strip * SW + (rem - bm * SW);
    const int blockM = bm * TILE;
    const int blockN = bn * TILE;

    const int t    = threadIdx.x;
    const int lane = t & 63;
    const int wave = t >> 6;
    const int wm   = (wave >> 1) * 64;
    const int wn   = (wave & 1) * 64;
    const int r32  = lane & 31;       // row within 32x32 tile (A) / col (B)
    const int half = lane >> 5;       // k-half selector
    const int kx   = r32 & 7;         // xor key for swizzled frag reads

    f32x16 acc[2][2] = {};

    const bf16_t* Ab = A + sAb * (long)b;
    const bf16_t* Bb = B + sBb * (long)b;

    // staging: stored chunk c = t + j*256; row=c>>3, stored kc=c&7,
    // logical kc = stored ^ (row&7). 4 chunks each for A and B per K-step.
    const bf16_t* gA[4]; const bf16_t* gB[4];
    bf16_t* lA[4]; bf16_t* lB[4];
    #pragma unroll
    for (int j = 0; j < 4; j++) {
        int c   = t + j * 256;
        int row = c >> 3;
        int kcl = (c & 7) ^ (row & 7);
        gA[j] = Ab + (long)(blockM + row) * K + kcl * 8;
        gB[j] = Bb + (long)(blockN + row) * K + kcl * 8;
        lA[j] = &As[c * 8];
        lB[j] = &Bs[c * 8];
    }

    for (int k0 = 0; k0 < K; k0 += BK) {
        #pragma unroll
        for (int j = 0; j < 4; j++) async_copy16(gA[j] + k0, lA[j]);
        #pragma unroll
        for (int j = 0; j < 4; j++) async_copy16(gB[j] + k0, lB[j]);
        __syncthreads();

        #pragma unroll
        for (int ks = 0; ks < 4; ks++) {
            const int kc = ks * 2 + half;       // logical 8-elem chunk in BK
            bf16x8 af[2], bfr[2];
            #pragma unroll
            for (int i = 0; i < 2; i++) {
                int R = wm + i * 32 + r32;
                af[i] = *(const bf16x8*)&As[(R * 8 + (kc ^ kx)) * 8];
            }
            #pragma unroll
            for (int j = 0; j < 2; j++) {
                int C = wn + j * 32 + r32;
                bfr[j] = *(const bf16x8*)&Bs[(C * 8 + (kc ^ kx)) * 8];
            }
            #pragma unroll
            for (int i = 0; i < 2; i++)
                #pragma unroll
                for (int j = 0; j < 2; j++)
                    acc[i][j] = __builtin_amdgcn_mfma_f32_32x32x16_bf16(
                                    af[i], bfr[j], acc[i][j], 0, 0, 0);
        }
        __syncthreads();
    }

    // epilogue: C/D layout col=lane&31, row=(reg&3)+8*(reg>>2)+4*half
    float*  Cf = (float*) Cp + sCb * (long)b;
    bf16_t* Ch = (bf16_t*)Cp + sCb * (long)b;
    #pragma unroll
    for (int ti = 0; ti < 2; ti++) {
        #pragma unroll
        for (int tj = 0; tj < 2; tj++) {
            const int gcol = blockN + wn + tj * 32 + r32;
            float bc = 0.f;
            if (BIAS_MODE == 1) bc = bias[gcol];
            #pragma unroll
            for (int reg = 0; reg < 16; reg++) {
                const int grow = blockM + wm + ti * 32
                               + (reg & 3) + 8 * (reg >> 2) + 4 * half;
                float vv = acc[ti][tj][reg];
                if (BIAS_MODE == 1) vv += bc;
                if (BIAS_MODE == 2) vv += bias[grow];
                if (RELU) vv = fmaxf(vv, 0.f);
                if (OUT_F32) Cf[(long)grow * ldc + gcol] = vv;
                else         Ch[(long)grow * ldc + gcol] = (bf16_t)vv;
            }
        }
    }
}

// One-shot fp32 -> bf16 cast of q,k,v,Wq,Wk,Wv into workspace.
__global__ __launch_bounds__(256)
void cast_all_kernel(const float* __restrict__ q, const float* __restrict__ k,
                     const float* __restrict__ v, const float* __restrict__ Wq,
                     const float* __restrict__ Wk, const float* __restrict__ Wv,
                     bf16_t* __restrict__ ws)
{
    const long BIG = 1048576;   // 8192*1024 / 8
    const long SMALL = 131072;  // 1024*1024 / 8
    long id = (long)blockIdx.x * blockDim.x + threadIdx.x;
    const float* src; bf16_t* dst;
    if (id < 3 * BIG) {
        int s = (int)(id / BIG);
        long off = (id - (long)s * BIG) * 8;
        src = (s == 0 ? q : s == 1 ? k : v) + off;
        dst = ws + (long)s * 8388608 + off;
    } else {
        long id2 = id - 3 * BIG;
        int s = (int)(id2 / SMALL);
        long off = (id2 - (long)s * SMALL) * 8;
        src = (s == 0 ? Wq : s == 1 ? Wk : Wv) + off;
        dst = ws + 25165824L + (long)s * 1048576 + off;
    }
    float4 v0 = ((const float4*)src)[0];
    float4 v1 = ((const float4*)src)[1];
    alignas(16) bf16_t o[8];
    o[0]=(bf16_t)v0.x; o[1]=(bf16_t)v0.y; o[2]=(bf16_t)v0.z; o[3]=(bf16_t)v0.w;
    o[4]=(bf16_t)v1.x; o[5]=(bf16_t)v1.y; o[6]=(bf16_t)v1.z; o[7]=(bf16_t)v1.w;
    *(uint4*)dst = *(const uint4*)o;
}

extern "C" void kernel_launch(void* const* d_in, const int* in_sizes, int n_in,
                              void* d_out, int out_size, void* d_ws, size_t ws_size,
                              hipStream_t stream)
{
    const float* q   = (const float*)d_in[0];
    const float* k   = (const float*)d_in[1];
    const float* v   = (const float*)d_in[2];
    const float* Wq  = (const float*)d_in[3];
    const float* bq  = (const float*)d_in[4];
    const float* Wk  = (const float*)d_in[5];
    const float* bk  = (const float*)d_in[6];
    const float* Wv  = (const float*)d_in[7];
    const float* bv  = (const float*)d_in[8];

    const int B = 4, S = 2048, D = 1024;
    const int BS = B * S; // 8192

    // workspace (bf16 element offsets):
    //   qb 0, kb 8388608, vb 16777216 (dead after their GEMM; Sc aliases qb+kb)
    //   Wqb 25165824, Wkb 26214400, Wvb 27262976
    //   Qp 28311552, Kp 36700160, VpT 45088768   (total ~107 MB)
    bf16_t* ws  = (bf16_t*)d_ws;
    bf16_t* qb  = ws;
    bf16_t* kb  = ws + 8388608L;
    bf16_t* vb  = ws + 16777216L;
    bf16_t* Wqb = ws + 25165824L;
    bf16_t* Wkb = ws + 26214400L;
    bf16_t* Wvb = ws + 27262976L;
    bf16_t* Qp  = ws + 28311552L;
    bf16_t* Kp  = ws + 36700160L;
    bf16_t* VpT = ws + 45088768L;
    bf16_t* Sc  = ws;              // aliases qb+kb (both dead by step 5)

    dim3 blk(256);

    // 1) cast everything to bf16 (R6/R8 lesson: pre-cast beats any in-flight cvt)
    cast_all_kernel<<<dim3(13824), blk, 0, stream>>>(q, k, v, Wq, Wk, Wv, ws);

    // 2) Qp = qb @ Wqb^T + bq   [M=8192, N=1024, K=1024]  SW=4 (R5-exact)
    gemm_bt<4, false, false, 1><<<dim3(D / TILE, BS / TILE, 1), blk, 0, stream>>>(
        qb, Wqb, bq, Qp, D, D, 0L, 0L, 0L);

    // 3) Kp = kb @ Wkb^T + bk
    gemm_bt<4, false, false, 1><<<dim3(D / TILE, BS / TILE, 1), blk, 0, stream>>>(
        kb, Wkb, bk, Kp, D, D, 0L, 0L, 0L);

    // 4) VpT[b] = (v_b @ Wv^T + bv)^T : A=Wvb [1024,1024], B=vb_b [2048,1024]
    gemm_bt<4, false, false, 2><<<dim3(S / TILE, D / TILE, B), blk, 0, stream>>>(
        Wvb, vb, bv, VpT, D, S, 0L, (long)S * D, (long)D * S);

    // 5) Sc[b] = relu(Qp_b @ Kp_b^T)  [2048 x 2048, K=1024]  SW=8 (L2 strips)
    gemm_bt<8, false, true, 0><<<dim3(S / TILE, S / TILE, B), blk, 0, stream>>>(
        Qp, Kp, nullptr, Sc, D, S, (long)S * D, (long)S * D, (long)S * S);

    // 6) out[b] = Sc_b @ VpT_b^T  [2048 x 1024, K=2048]  SW=8, fp32 out
    gemm_bt<8, true, false, 0><<<dim3(D / TILE, S / TILE, B), blk, 0, stream>>>(
        Sc, VpT, nullptr, d_out, S, D, (long)S * S, (long)D * S, (long)S * D);
}